// Round 8
// baseline (605.107 us; speedup 1.0000x reference)
//
#include <hip/hip_runtime.h>
#include <hip/hip_bf16.h>
#include <cstdint>

static __device__ __forceinline__ float lo16(uint32_t u){ return __uint_as_float(u << 16); }
static __device__ __forceinline__ float hi16(uint32_t u){ return __uint_as_float(u & 0xffff0000u); }
static __device__ __forceinline__ uint32_t f2bf(float x){
    uint32_t u = __float_as_uint(x);
    return (u + 0x7fffu + ((u >> 16) & 1u)) >> 16;
}
static __device__ __forceinline__ uint32_t pack2(float a, float b){
    return f2bf(a) | (f2bf(b) << 16);
}
// LDS swizzle: row i (16 uints), rotate by (i>>1) -> hot patterns <=2-way conflicts (free)
#define SW(i, dp) (((i) << 4) + (((dp) + ((i) >> 1)) & 15))

// ---------------- K1: kf fp32 + packed bf16 ----------------
__global__ __launch_bounds__(256) void k_kf(const float* __restrict__ k,
    const float* __restrict__ Wk, const float* __restrict__ bk,
    float* __restrict__ kf_f, uint32_t* __restrict__ kf_pack)
{
    __shared__ float Wk_s[256*32];
    __shared__ float bk_s[32];
    int t = threadIdx.x;
    for (int L = t; L < 8192; L += 256) Wk_s[L] = Wk[L];
    if (t < 32) bk_s[t] = bk[t];
    __syncthreads();
    int blk = blockIdx.x;                 // 128 blocks
    int b = blk >> 6, i0 = (blk & 63) * 8;
    int d = t & 31, sub = t >> 5;
    int i = i0 + sub;
    const float* kb = k + (size_t)b * 131072;
    float acc = bk_s[d];
    #pragma unroll 8
    for (int c = 0; c < 256; ++c)
        acc += kb[c*512 + i] * Wk_s[c*32 + d];
    kf_f[(b*512 + i)*32 + d] = acc;
    float accO = __shfl_xor(acc, 1, 64);       // lane parity == d parity
    if ((d & 1) == 0)
        kf_pack[(b*512 + i)*16 + (d >> 1)] = pack2(acc, accO);
}

// ---------------- K2: k_norm[b,d] ----------------
__global__ __launch_bounds__(256) void k_knorm(const float* __restrict__ kf_f,
                                               float* __restrict__ knorm)
{
    __shared__ float red[8][32];
    int b = blockIdx.x;
    int t = threadIdx.x, d = t & 31, sub = t >> 5;
    float s = 0.f;
    for (int it = 0; it < 64; ++it){
        float v = kf_f[(b*512 + sub + it*8)*32 + d];
        s += v * v;
    }
    red[sub][d] = s;
    __syncthreads();
    if (sub == 0){
        float tot = 0.f;
        #pragma unroll
        for (int u = 0; u < 8; ++u) tot += red[u][d];
        knorm[b*32 + d] = sqrtf(tot);
    }
}

// ---------------- K3: qb packed bf16 + denom[b,g] ----------------
__global__ __launch_bounds__(512) void k_qb(const float* __restrict__ q,
    const float* __restrict__ Wq, const float* __restrict__ bq,
    const float* __restrict__ knorm,
    uint32_t* __restrict__ qb_pack, float* __restrict__ denomv)
{
    __shared__ float Wq_s[1024], bq_s[32], red[16][32], qn_s[32];
    int t = threadIdx.x;
    int blk = blockIdx.x;                  // 128 blocks = (b,g)
    int b = blk >> 6, g = blk & 63;
    int bh = g >> 4, bw = (g >> 2) & 3, bd = g & 3;
    for (int L = t; L < 1024; L += 512) Wq_s[L] = Wq[L];
    if (t < 32) bq_s[t] = bq[t];
    __syncthreads();
    int d = t & 31, sub = t >> 5;          // sub 0..15
    const float* qbase = q + (size_t)b * 1048576;
    float ssq = 0.f;
    uint32_t* qb_out = qb_pack + (size_t)blk * 8192;
    for (int it = 0; it < 32; ++it){
        int j = it*16 + sub;
        int ih = j >> 6, iw = (j >> 3) & 7, id = j & 7;
        const float* qj = qbase + (bh*8+ih)*1024 + (bw*8+iw)*32 + bd*8 + id;
        float acc = bq_s[d];
        #pragma unroll
        for (int c = 0; c < 32; ++c)
            acc += qj[c*32768] * Wq_s[c*32 + d];
        ssq += acc * acc;                  // fp32 norm (matches ref)
        float accO = __shfl_xor(acc, 1, 64);
        if ((d & 1) == 0) qb_out[j*16 + (d >> 1)] = pack2(acc, accO);
    }
    red[sub][d] = ssq;
    __syncthreads();
    if (sub == 0){
        float tot = 0.f;
        #pragma unroll
        for (int u = 0; u < 16; ++u) tot += red[u][d];
        qn_s[d] = sqrtf(tot);
    }
    __syncthreads();
    if (t == 0){
        float s = 0.f;
        for (int d2 = 0; d2 < 32; ++d2) s += knorm[b*32 + d2] * qn_s[d2];
        denomv[blk] = s + 1e-4f;
    }
}

// ---------------- K4: attention per (bg, j-quarter); expm1-centered PV ----------------
// grid 512, block 256; 64 KiB static LDS -> 2 blocks/CU, 8 waves/CU
__global__ __launch_bounds__(256) void k_attn(const uint32_t* __restrict__ kf_pack,
    const uint32_t* __restrict__ qb_pack, const float* __restrict__ denomv,
    float* __restrict__ out_raw)
{
    __shared__ uint32_t kfs[8192];   // 32 KiB
    __shared__ uint32_t qbs[8192];   // 32 KiB
    int t = threadIdx.x;
    int blk = blockIdx.x;            // 512 blocks
    int bg = blk >> 2, jq = blk & 3;
    int b = bg >> 6;
    const uint32_t* kfg = kf_pack + b * 8192;
    const uint32_t* qbg = qb_pack + (size_t)bg * 8192;
    for (int L = t; L < 8192; L += 256){
        int i = L >> 4, dp = L & 15;
        kfs[SW(i,dp)] = kfg[L];
        qbs[SW(i,dp)] = qbg[L];
    }
    __syncthreads();
    float rden = 1.0f / denomv[bg];
    int lane = t & 63, wave = t >> 6;
    int half = lane >> 5, l32 = lane & 31, d = l32;
    int dp0 = d >> 1;
    int sh_ = (d & 1) ? 0 : 16;      // extract channel d from packed pair
    int ibase = half * 256;
    int srcbase = lane & 32;
    int j0 = jq*128 + wave*32;
    float* orow = out_raw + (size_t)bg * 16384;
    // vsum[d] = sum_i v[i,d] over all 512 i (j-independent)
    float vsum;
    {
        float acc = 0.f;
        #pragma unroll 8
        for (int ii = 0; ii < 256; ++ii){
            uint32_t w = qbs[SW(ibase + ii, dp0)];
            acc += __uint_as_float((w << sh_) & 0xffff0000u);
        }
        acc += __shfl_xor(acc, 32, 64);
        vsum = acc;
    }
    for (int r2 = 0; r2 < 16; ++r2){
        int jA = j0 + r2*2, jB = jA + 1;
        float qfA[32], qfB[32];
        #pragma unroll
        for (int dp = 0; dp < 16; ++dp){
            uint32_t uA = qbs[SW(jA,dp)];            // uniform addr -> broadcast
            uint32_t uB = qbs[SW(jB,dp)];
            qfA[2*dp] = lo16(uA); qfA[2*dp+1] = hi16(uA);
            qfB[2*dp] = lo16(uB); qfB[2*dp+1] = hi16(uB);
        }
        // sim: lane owns i = half*256 + u*32 + l32
        float sA[8], sB[8];
        #pragma unroll
        for (int u = 0; u < 8; ++u){
            int i = ibase + u*32 + l32;
            float aA = 0.f, aB = 0.f;
            #pragma unroll
            for (int dp = 0; dp < 16; ++dp){
                uint32_t kv = kfs[SW(i,dp)];
                float klo = lo16(kv), khi = hi16(kv);
                aA += klo*qfA[2*dp] + khi*qfA[2*dp+1];
                aB += klo*qfB[2*dp] + khi*qfB[2*dp+1];
            }
            sA[u] = aA * rden; sB[u] = aB * rden;
        }
        // wave max over all 512 i
        float mA = sA[0], mB = sB[0];
        #pragma unroll
        for (int u = 1; u < 8; ++u){ mA = fmaxf(mA, sA[u]); mB = fmaxf(mB, sB[u]); }
        #pragma unroll
        for (int off = 32; off > 0; off >>= 1){
            mA = fmaxf(mA, __shfl_xor(mA, off, 64));
            mB = fmaxf(mB, __shfl_xor(mB, off, 64));
        }
        // e = expm1(s - m) via cubic poly (|x| <= ~5e-3); S = 512 + sum(e)
        float esA = 0.f, esB = 0.f;
        #pragma unroll
        for (int u = 0; u < 8; ++u){
            float xA = sA[u] - mA;
            float xB = sB[u] - mB;
            sA[u] = xA + xA*xA*(0.5f + xA*(1.0f/6.0f));   // reuse regs as e
            sB[u] = xB + xB*xB*(0.5f + xB*(1.0f/6.0f));
            esA += sA[u]; esB += sB[u];
        }
        #pragma unroll
        for (int off = 32; off > 0; off >>= 1){
            esA += __shfl_xor(esA, off, 64);
            esB += __shfl_xor(esB, off, 64);
        }
        float rlA = 1.0f / (512.f + esA);
        float rlB = 1.0f / (512.f + esB);
        // delta-PV: acc = sum_i e_i * v[i,d]; e fetched from owner lane via shfl
        float accA = 0.f, accB = 0.f;
        #pragma unroll
        for (int u = 0; u < 8; ++u){
            #pragma unroll 4
            for (int t2 = 0; t2 < 32; ++t2){
                uint32_t w = qbs[SW(ibase + u*32 + t2, dp0)];
                float v = __uint_as_float((w << sh_) & 0xffff0000u);
                float ea = __shfl(sA[u], srcbase + t2, 64);
                float eb = __shfl(sB[u], srcbase + t2, 64);
                accA += ea * v;
                accB += eb * v;
            }
        }
        accA += __shfl_xor(accA, 32, 64);
        accB += __shfl_xor(accB, 32, 64);
        if (half == 0){
            orow[jA*32 + d] = (vsum + accA) * rlA;
            orow[jB*32 + d] = (vsum + accB) * rlB;
        }
    }
}

// ---------------- K5: min-max renorm over j + transposed fp32 write vt[bg][c*512+j] ------
__global__ __launch_bounds__(256) void k_renorm(const float* __restrict__ out_raw,
                                                float* __restrict__ vt)
{
    __shared__ float mnr[8][32], mxr[8][32], mn_s[32], sc_s[32];
    int t = threadIdx.x;
    int bg = blockIdx.x;                         // 128 blocks
    const float* src = out_raw + (size_t)bg * 16384;
    int d = t & 31, sub = t >> 5;
    float mn = 3e38f, mx = -3e38f;
    for (int it = 0; it < 64; ++it){
        float v = src[(sub + it*8)*32 + d];
        mn = fminf(mn, v); mx = fmaxf(mx, v);
    }
    mnr[sub][d] = mn; mxr[sub][d] = mx;
    __syncthreads();
    if (sub == 0){
        #pragma unroll
        for (int u = 1; u < 8; ++u){ mn = fminf(mn, mnr[u][d]); mx = fmaxf(mx, mxr[u][d]); }
        mn_s[d] = mn;
        sc_s[d] = 1.0f / (mx - mn + 1e-4f);
    }
    __syncthreads();
    float* dst = vt + (size_t)bg * 16384;
    for (int L = t; L < 16384; L += 256){
        int c = L >> 9, j = L & 511;
        dst[L] = (src[j*32 + c] - mn_s[c]) * sc_s[c];
    }
}

// ---------------- K6: scrambled gather + Wp projection + fp32 store ----------------
__global__ __launch_bounds__(256) void k_proj(const float* __restrict__ vt,
    const float* __restrict__ Wp, const float* __restrict__ bp,
    float* __restrict__ out)
{
    __shared__ float Wp_s[1024], bp_s[32];
    __shared__ float sh_v[8][32], sh_o[8][32];
    int t = threadIdx.x;
    if (t < 32) bp_s[t] = bp[t];
    for (int L = t; L < 1024; L += 256) Wp_s[L] = Wp[L];
    int blk = blockIdx.x;                        // 8192 blocks
    int b = blk >> 12, p0 = (blk & 4095) * 8;
    int c = t & 31, ip = t >> 5;
    int p = p0 + ip;
    int h = p >> 10, w = (p >> 5) & 31, dsp = p & 31;
    int f = (h >> 3)*262144 + (w >> 3)*65536 + (dsp >> 3)*16384
          + (h & 7)*2048 + (w & 7)*256 + (dsp & 7)*32;
    float vv = vt[(size_t)b * 1048576 + f + c];
    __syncthreads();
    sh_v[ip][c] = vv;
    __syncthreads();
    float acc = bp_s[c];
    #pragma unroll
    for (int cc = 0; cc < 32; ++cc)
        acc += sh_v[ip][cc] * Wp_s[cc*32 + c];
    sh_o[ip][c] = acc;
    __syncthreads();
    int ee = t >> 3, pi = t & 7;
    out[((size_t)(b*32 + ee) << 15) + p0 + pi] = sh_o[pi][ee];
}

extern "C" void kernel_launch(void* const* d_in, const int* in_sizes, int n_in,
                              void* d_out, int out_size, void* d_ws, size_t ws_size,
                              hipStream_t stream)
{
    const float* q  = (const float*)d_in[0];
    const float* k  = (const float*)d_in[1];
    const float* Wq = (const float*)d_in[2];
    const float* bq = (const float*)d_in[3];
    const float* Wk = (const float*)d_in[4];
    const float* bk = (const float*)d_in[5];
    const float* Wp = (const float*)d_in[6];
    const float* bp = (const float*)d_in[7];

    float* base      = (float*)d_ws;
    float* kf_f      = base;                            // 32768 f
    float* knorm     = base + 32768;                    // 64 f
    float* denomv    = base + 32832;                    // 128 f
    uint32_t* kf_pack = (uint32_t*)(base + 32960);      // 16384 u32
    uint32_t* qb_pack = (uint32_t*)(base + 49344);      // 1,048,576 u32
    float* out_raw   = base + 1097920;                  // 2,097,152 f
    float* vt        = base + 3195072;                  // 2,097,152 f (~21.2 MB total)
    float* outp      = (float*)d_out;

    hipLaunchKernelGGL(k_kf,     dim3(128),  dim3(256), 0, stream, k, Wk, bk, kf_f, kf_pack);
    hipLaunchKernelGGL(k_knorm,  dim3(2),    dim3(256), 0, stream, kf_f, knorm);
    hipLaunchKernelGGL(k_qb,     dim3(128),  dim3(512), 0, stream, q, Wq, bq, knorm, qb_pack, denomv);
    hipLaunchKernelGGL(k_attn,   dim3(512),  dim3(256), 0, stream, kf_pack, qb_pack, denomv, out_raw);
    hipLaunchKernelGGL(k_renorm, dim3(128),  dim3(256), 0, stream, out_raw, vt);
    hipLaunchKernelGGL(k_proj,   dim3(8192), dim3(256), 0, stream, vt, Wp, bp, outp);
}

// Round 9
// 197.347 us; speedup vs baseline: 3.0662x; 3.0662x over previous
//
#include <hip/hip_runtime.h>
#include <hip/hip_bf16.h>
#include <cstdint>

typedef __attribute__((ext_vector_type(8))) short bf16x8;
typedef __attribute__((ext_vector_type(4))) float f32x4;

static __device__ __forceinline__ uint32_t f2bf(float x){
    uint32_t u = __float_as_uint(x);
    return (u + 0x7fffu + ((u >> 16) & 1u)) >> 16;
}
static __device__ __forceinline__ uint32_t pack2(float a, float b){
    return f2bf(a) | (f2bf(b) << 16);
}

// ---------------- K1: kf fp32 + packed bf16 ----------------
__global__ __launch_bounds__(256) void k_kf(const float* __restrict__ k,
    const float* __restrict__ Wk, const float* __restrict__ bk,
    float* __restrict__ kf_f, uint32_t* __restrict__ kf_pack)
{
    __shared__ float Wk_s[256*32];
    __shared__ float bk_s[32];
    int t = threadIdx.x;
    for (int L = t; L < 8192; L += 256) Wk_s[L] = Wk[L];
    if (t < 32) bk_s[t] = bk[t];
    __syncthreads();
    int blk = blockIdx.x;                 // 128 blocks
    int b = blk >> 6, i0 = (blk & 63) * 8;
    int d = t & 31, sub = t >> 5;
    int i = i0 + sub;
    const float* kb = k + (size_t)b * 131072;
    float acc = bk_s[d];
    #pragma unroll 8
    for (int c = 0; c < 256; ++c)
        acc += kb[c*512 + i] * Wk_s[c*32 + d];
    kf_f[(b*512 + i)*32 + d] = acc;
    float accO = __shfl_xor(acc, 1, 64);       // lane parity == d parity
    if ((d & 1) == 0)
        kf_pack[(b*512 + i)*16 + (d >> 1)] = pack2(acc, accO);
}

// ---------------- K2: k_norm[b,d] ----------------
__global__ __launch_bounds__(256) void k_knorm(const float* __restrict__ kf_f,
                                               float* __restrict__ knorm)
{
    __shared__ float red[8][32];
    int b = blockIdx.x;
    int t = threadIdx.x, d = t & 31, sub = t >> 5;
    float s = 0.f;
    for (int it = 0; it < 64; ++it){
        float v = kf_f[(b*512 + sub + it*8)*32 + d];
        s += v * v;
    }
    red[sub][d] = s;
    __syncthreads();
    if (sub == 0){
        float tot = 0.f;
        #pragma unroll
        for (int u = 0; u < 8; ++u) tot += red[u][d];
        knorm[b*32 + d] = sqrtf(tot);
    }
}

// ---------------- K3: qb packed bf16 + denom[b,g] + vsum[b,g,d] ----------------
__global__ __launch_bounds__(512) void k_qb(const float* __restrict__ q,
    const float* __restrict__ Wq, const float* __restrict__ bq,
    const float* __restrict__ knorm,
    uint32_t* __restrict__ qb_pack, float* __restrict__ denomv,
    float* __restrict__ vsum)
{
    __shared__ float Wq_s[1024], bq_s[32], red[16][32], vs[16][32], qn_s[32];
    int t = threadIdx.x;
    int blk = blockIdx.x;                  // 128 blocks = (b,g)
    int b = blk >> 6, g = blk & 63;
    int bh = g >> 4, bw = (g >> 2) & 3, bd = g & 3;
    for (int L = t; L < 1024; L += 512) Wq_s[L] = Wq[L];
    if (t < 32) bq_s[t] = bq[t];
    __syncthreads();
    int d = t & 31, sub = t >> 5;          // sub 0..15
    const float* qbase = q + (size_t)b * 1048576;
    float ssq = 0.f, vsp = 0.f;
    uint32_t* qb_out = qb_pack + (size_t)blk * 8192;
    for (int it = 0; it < 32; ++it){
        int j = it*16 + sub;
        int ih = j >> 6, iw = (j >> 3) & 7, id = j & 7;
        const float* qj = qbase + (bh*8+ih)*1024 + (bw*8+iw)*32 + bd*8 + id;
        float acc = bq_s[d];
        #pragma unroll
        for (int c = 0; c < 32; ++c)
            acc += qj[c*32768] * Wq_s[c*32 + d];
        ssq += acc * acc;
        vsp += acc;
        float accO = __shfl_xor(acc, 1, 64);
        if ((d & 1) == 0) qb_out[j*16 + (d >> 1)] = pack2(acc, accO);
    }
    red[sub][d] = ssq;
    vs[sub][d] = vsp;
    __syncthreads();
    if (sub == 0){
        float tot = 0.f, vtot = 0.f;
        #pragma unroll
        for (int u = 0; u < 16; ++u){ tot += red[u][d]; vtot += vs[u][d]; }
        qn_s[d] = sqrtf(tot);
        vsum[blk*32 + d] = vtot;
    }
    __syncthreads();
    if (t == 0){
        float s = 0.f;
        for (int d2 = 0; d2 < 32; ++d2) s += knorm[b*32 + d2] * qn_s[d2];
        denomv[blk] = s + 1e-4f;
    }
}

// ---------------- K4: MFMA attention, zero-centered expm1 softmax ----------------
// grid 512 = (bg, i-half, j-half); block 256 = 4 waves; LDS 64 KB.
// Emits partials: pden[bg2][j] = sum_{i in half} e_ji ; pnum[bg2][j][c] = sum e_ji*v_ic
__global__ __launch_bounds__(256) void k_attn_mfma(const uint32_t* __restrict__ kf_pack,
    const uint32_t* __restrict__ qb_pack, const float* __restrict__ denomv,
    float* __restrict__ pden, float* __restrict__ pnum)
{
    __shared__ uint32_t kfs32[4096];     // kf[i 256][d 32] bf16, swizzled
    __shared__ uint16_t qbT16[8192];     // qb^T[d 32][j 256] (Q role)
    __shared__ uint16_t qbV16[8192];     // qb^T[c 32][i 256] (V role)
    __shared__ uint16_t Ps16[8192];      // per-wave P[16 j][128 i] bf16
    int t = threadIdx.x;
    int blk = blockIdx.x;
    int bg = blk >> 2, ihalf = (blk >> 1) & 1, jhalf = blk & 1;
    int b = bg >> 6;
    // ---- stage kf (this block's i-half) ----
    {
        const uint32_t* src = kf_pack + b*8192 + ihalf*4096;
        for (int m = 0; m < 16; ++m){
            int flat = m*256 + t;
            uint32_t v = src[flat];
            int i = flat >> 4, dp = flat & 15;
            kfs32[i*16 + (((dp>>2) ^ (i&3)) & 3)*4 + (dp&3)] = v;
        }
    }
    // ---- stage qbT (j-half, Q role) and qbV (i-half, V role) ----
    {
        const uint32_t* srcJ = qb_pack + (size_t)bg*8192 + jhalf*4096;
        const uint32_t* srcI = qb_pack + (size_t)bg*8192 + ihalf*4096;
        for (int m = 0; m < 16; ++m){
            int flat = m*256 + t;
            int col = flat >> 4, dp = flat & 15;
            uint32_t vj = srcJ[flat];
            int d0 = 2*dp, d1 = 2*dp + 1;
            qbT16[d0*256 + (((col>>3) ^ (d0&7)) & 31)*8 + (col&7)] = (uint16_t)(vj & 0xffffu);
            qbT16[d1*256 + (((col>>3) ^ (d1&7)) & 31)*8 + (col&7)] = (uint16_t)(vj >> 16);
            uint32_t vi = srcI[flat];
            qbV16[d0*256 + (((col>>3) ^ (d0&7)) & 31)*8 + (col&7)] = (uint16_t)(vi & 0xffffu);
            qbV16[d1*256 + (((col>>3) ^ (d1&7)) & 31)*8 + (col&7)] = (uint16_t)(vi >> 16);
        }
    }
    __syncthreads();
    float rden = 1.0f / denomv[bg];
    int wave = t >> 6, lane = t & 63;
    int ln15 = lane & 15, quad = lane >> 4;
    uint16_t* Pw = Ps16 + wave*2048;
    int bg2 = bg*2 + ihalf;
    // each wave: 4 j-tiles
    for (int jt4 = 0; jt4 < 4; ++jt4){
        int jtile = wave*4 + jt4;
        int jloc = jtile*16 + ln15;              // j within half [0,256)
        // sim A-frag: A[m=j][k=d], k = quad*8 + jj
        union { bf16x8 v; uint16_t u[8]; } afr;
        #pragma unroll
        for (int jj = 0; jj < 8; ++jj){
            int d = quad*8 + jj;
            afr.u[jj] = qbT16[d*256 + (((jloc>>3) ^ (d&7)) & 31)*8 + (jloc&7)];
        }
        f32x4 pv0 = {0.f,0.f,0.f,0.f}, pv1 = {0.f,0.f,0.f,0.f};
        float pdn[4] = {0.f,0.f,0.f,0.f};
        for (int ch = 0; ch < 2; ++ch){
            // ---- sim: 8 i-tiles of 16 ----
            f32x4 sacc[8];
            #pragma unroll
            for (int it = 0; it < 8; ++it){
                int i = (ch*8 + it)*16 + ln15;   // i within half
                bf16x8 bfr = *(__shared__ bf16x8*)&kfs32[(i*16 + ((quad ^ (i&3)) & 3)*4)];
                f32x4 z = {0.f,0.f,0.f,0.f};
                sacc[it] = __builtin_amdgcn_mfma_f32_16x16x32_bf16(afr.v, bfr, z, 0, 0, 0);
            }
            // ---- e = expm1(x), write P chunk, accumulate pden ----
            #pragma unroll
            for (int it = 0; it < 8; ++it){
                #pragma unroll
                for (int r = 0; r < 4; ++r){
                    float x = sacc[it][r] * rden;
                    float e = x + x*x*(0.5f + x*(1.0f/6.0f));
                    pdn[r] += e;
                    int jrow = quad*4 + r;               // row in j-tile
                    int il = it*16 + ln15;               // i in chunk [0,128)
                    Pw[jrow*128 + (((il>>3) ^ (jrow&7)) & 15)*8 + (il&7)] = (uint16_t)f2bf(e);
                }
            }
            __threadfence_block();   // drain LDS writes before fragment reads
            // ---- PV: out^T[c][j] += V^T * P^T  (K = 128, 4 ksteps) ----
            #pragma unroll
            for (int ks = 0; ks < 4; ++ks){
                int i0 = ks*32 + quad*8;                 // i in chunk
                bf16x8 bp = *(__shared__ bf16x8*)&Pw[ln15*128 + (((i0>>3) ^ (ln15&7)) & 15)*8];
                int ig = ch*128 + i0;                    // i within half [0,256)
                int c0 = ln15;
                bf16x8 av0 = *(__shared__ bf16x8*)&qbV16[c0*256 + (((ig>>3) ^ (c0&7)) & 31)*8];
                int c1 = 16 + ln15;
                bf16x8 av1 = *(__shared__ bf16x8*)&qbV16[c1*256 + (((ig>>3) ^ (c1&7)) & 31)*8];
                pv0 = __builtin_amdgcn_mfma_f32_16x16x32_bf16(av0, bp, pv0, 0, 0, 0);
                pv1 = __builtin_amdgcn_mfma_f32_16x16x32_bf16(av1, bp, pv1, 0, 0, 0);
            }
        }
        // ---- pden: reduce over the 16 lanes sharing this j-group ----
        #pragma unroll
        for (int r = 0; r < 4; ++r){
            float s = pdn[r];
            s += __shfl_xor(s, 1, 64);
            s += __shfl_xor(s, 2, 64);
            s += __shfl_xor(s, 4, 64);
            s += __shfl_xor(s, 8, 64);
            pdn[r] = s;
        }
        int jbase = jhalf*256 + jtile*16;
        if (ln15 == 0){
            #pragma unroll
            for (int r = 0; r < 4; ++r)
                pden[(size_t)bg2*512 + jbase + quad*4 + r] = pdn[r];
        }
        // ---- pnum: D[m=c][n=j]: col=lane&15=j, row=quad*4+r=c ----
        int j = jbase + ln15;
        #pragma unroll
        for (int r = 0; r < 4; ++r){
            pnum[((size_t)bg2*512 + j)*32 + (quad*4 + r)]      = pv0[r];
            pnum[((size_t)bg2*512 + j)*32 + (16 + quad*4 + r)] = pv1[r];
        }
    }
}

// ---------------- K5: combine partials + min-max renorm -> vt[bg][c*512+j] ----------------
__global__ __launch_bounds__(256) void k_comb(const float* __restrict__ pden,
    const float* __restrict__ pnum, const float* __restrict__ vsum,
    float* __restrict__ vt)
{
    __shared__ float mnr[8][32], mxr[8][32], mn_s[32], sc_s[32];
    int t = threadIdx.x;
    int bg = blockIdx.x;                         // 128 blocks
    const float* pn0 = pnum + (size_t)(bg*2+0)*512*32;
    const float* pn1 = pnum + (size_t)(bg*2+1)*512*32;
    const float* pd0 = pden + (size_t)(bg*2+0)*512;
    const float* pd1 = pden + (size_t)(bg*2+1)*512;
    int d = t & 31, sub = t >> 5;
    float vs = vsum[bg*32 + d];
    float mn = 3e38f, mx = -3e38f;
    for (int it = 0; it < 64; ++it){
        int j = sub + it*8;
        float o = (vs + pn0[j*32 + d] + pn1[j*32 + d])
                / (512.f + pd0[j] + pd1[j]);
        mn = fminf(mn, o); mx = fmaxf(mx, o);
    }
    mnr[sub][d] = mn; mxr[sub][d] = mx;
    __syncthreads();
    if (sub == 0){
        #pragma unroll
        for (int u = 1; u < 8; ++u){ mn = fminf(mn, mnr[u][d]); mx = fmaxf(mx, mxr[u][d]); }
        mn_s[d] = mn;
        sc_s[d] = 1.0f / (mx - mn + 1e-4f);
    }
    __syncthreads();
    float* dst = vt + (size_t)bg * 16384;
    for (int L = t; L < 16384; L += 256){
        int c = L >> 9, j = L & 511;
        float vsc = vsum[bg*32 + c];
        float o = (vsc + pn0[j*32 + c] + pn1[j*32 + c])
                / (512.f + pd0[j] + pd1[j]);
        dst[L] = (o - mn_s[c]) * sc_s[c];
    }
}

// ---------------- K6: scrambled gather + Wp projection + fp32 store ----------------
__global__ __launch_bounds__(256) void k_proj(const float* __restrict__ vt,
    const float* __restrict__ Wp, const float* __restrict__ bp,
    float* __restrict__ out)
{
    __shared__ float Wp_s[1024], bp_s[32];
    __shared__ float sh_v[8][32], sh_o[8][32];
    int t = threadIdx.x;
    if (t < 32) bp_s[t] = bp[t];
    for (int L = t; L < 1024; L += 256) Wp_s[L] = Wp[L];
    int blk = blockIdx.x;                        // 8192 blocks
    int b = blk >> 12, p0 = (blk & 4095) * 8;
    int c = t & 31, ip = t >> 5;
    int p = p0 + ip;
    int h = p >> 10, w = (p >> 5) & 31, dsp = p & 31;
    int f = (h >> 3)*262144 + (w >> 3)*65536 + (dsp >> 3)*16384
          + (h & 7)*2048 + (w & 7)*256 + (dsp & 7)*32;
    float vv = vt[(size_t)b * 1048576 + f + c];
    __syncthreads();
    sh_v[ip][c] = vv;
    __syncthreads();
    float acc = bp_s[c];
    #pragma unroll
    for (int cc = 0; cc < 32; ++cc)
        acc += sh_v[ip][cc] * Wp_s[cc*32 + c];
    sh_o[ip][c] = acc;
    __syncthreads();
    int ee = t >> 3, pi = t & 7;
    out[((size_t)(b*32 + ee) << 15) + p0 + pi] = sh_o[pi][ee];
}

extern "C" void kernel_launch(void* const* d_in, const int* in_sizes, int n_in,
                              void* d_out, int out_size, void* d_ws, size_t ws_size,
                              hipStream_t stream)
{
    const float* q  = (const float*)d_in[0];
    const float* k  = (const float*)d_in[1];
    const float* Wq = (const float*)d_in[2];
    const float* bq = (const float*)d_in[3];
    const float* Wk = (const float*)d_in[4];
    const float* bk = (const float*)d_in[5];
    const float* Wp = (const float*)d_in[6];
    const float* bp = (const float*)d_in[7];

    float* base      = (float*)d_ws;
    float* kf_f      = base;                            // 32768 f
    float* knorm     = base + 32768;                    // 64 f
    float* denomv    = base + 32832;                    // 128 f
    float* vsum      = base + 32960;                    // 4096 f
    uint32_t* kf_pack = (uint32_t*)(base + 37056);      // 16384 u32
    uint32_t* qb_pack = (uint32_t*)(base + 53440);      // 1,048,576 u32
    float* pden      = base + 1102016;                  // 131,072 f
    float* pnum      = base + 1233088;                  // 4,194,304 f
    float* vt        = base + 5427392;                  // 2,097,152 f (~30.1 MB total)
    float* outp      = (float*)d_out;

    hipLaunchKernelGGL(k_kf,        dim3(128),  dim3(256), 0, stream, k, Wk, bk, kf_f, kf_pack);
    hipLaunchKernelGGL(k_knorm,     dim3(2),    dim3(256), 0, stream, kf_f, knorm);
    hipLaunchKernelGGL(k_qb,        dim3(128),  dim3(512), 0, stream, q, Wq, bq, knorm, qb_pack, denomv, vsum);
    hipLaunchKernelGGL(k_attn_mfma, dim3(512),  dim3(256), 0, stream, kf_pack, qb_pack, denomv, pden, pnum);
    hipLaunchKernelGGL(k_comb,      dim3(128),  dim3(256), 0, stream, pden, pnum, vsum, vt);
    hipLaunchKernelGGL(k_proj,      dim3(8192), dim3(256), 0, stream, vt, Wp, bp, outp);
}

// Round 10
// 143.439 us; speedup vs baseline: 4.2186x; 1.3758x over previous
//
#include <hip/hip_runtime.h>
#include <hip/hip_bf16.h>
#include <cstdint>

typedef __attribute__((ext_vector_type(8))) short bf16x8;
typedef __attribute__((ext_vector_type(4))) float f32x4;

static __device__ __forceinline__ uint32_t f2bf(float x){
    uint32_t u = __float_as_uint(x);
    return (u + 0x7fffu + ((u >> 16) & 1u)) >> 16;
}
static __device__ __forceinline__ uint32_t pack2(float a, float b){
    return f2bf(a) | (f2bf(b) << 16);
}

// ---------------- K1: kf fp32 + packed bf16 ----------------
__global__ __launch_bounds__(256) void k_kf(const float* __restrict__ k,
    const float* __restrict__ Wk, const float* __restrict__ bk,
    float* __restrict__ kf_f, uint32_t* __restrict__ kf_pack)
{
    __shared__ float Wk_s[256*32];
    __shared__ float bk_s[32];
    int t = threadIdx.x;
    for (int L = t; L < 8192; L += 256) Wk_s[L] = Wk[L];
    if (t < 32) bk_s[t] = bk[t];
    __syncthreads();
    int blk = blockIdx.x;                 // 128 blocks
    int b = blk >> 6, i0 = (blk & 63) * 8;
    int d = t & 31, sub = t >> 5;
    int i = i0 + sub;
    const float* kb = k + (size_t)b * 131072;
    float acc = bk_s[d];
    #pragma unroll 8
    for (int c = 0; c < 256; ++c)
        acc += kb[c*512 + i] * Wk_s[c*32 + d];
    kf_f[(b*512 + i)*32 + d] = acc;
    float accO = __shfl_xor(acc, 1, 64);       // lane parity == d parity
    if ((d & 1) == 0)
        kf_pack[(b*512 + i)*16 + (d >> 1)] = pack2(acc, accO);
}

// ---------------- K2: k_norm[b,d] ----------------
__global__ __launch_bounds__(256) void k_knorm(const float* __restrict__ kf_f,
                                               float* __restrict__ knorm)
{
    __shared__ float red[8][32];
    int b = blockIdx.x;
    int t = threadIdx.x, d = t & 31, sub = t >> 5;
    float s = 0.f;
    for (int it = 0; it < 64; ++it){
        float v = kf_f[(b*512 + sub + it*8)*32 + d];
        s += v * v;
    }
    red[sub][d] = s;
    __syncthreads();
    if (sub == 0){
        float tot = 0.f;
        #pragma unroll
        for (int u = 0; u < 8; ++u) tot += red[u][d];
        knorm[b*32 + d] = sqrtf(tot);
    }
}

// ---------------- K3: qb packed bf16 + denom + vsum; LDS-staged q ----------------
__global__ __launch_bounds__(512) void k_qb(const float* __restrict__ q,
    const float* __restrict__ Wq, const float* __restrict__ bq,
    const float* __restrict__ knorm,
    uint32_t* __restrict__ qb_pack, float* __restrict__ denomv,
    float* __restrict__ vsum)
{
    __shared__ float Wq_s[1024], bq_s[32], q_s[8192];   // q_s: 32 c x 256 j (one half)
    __shared__ float red[16][32], vsx[16][32], qn_s[32];
    int t = threadIdx.x;
    int blk = blockIdx.x;                  // 128 blocks = (b,g)
    int b = blk >> 6, g = blk & 63;
    int bh = g >> 4, bw = (g >> 2) & 3, bd = g & 3;
    for (int L = t; L < 1024; L += 512) Wq_s[L] = Wq[L];
    if (t < 32) bq_s[t] = bq[t];
    int d = t & 31, sub = t >> 5;          // sub 0..15
    const float* qbase = q + (size_t)b * 1048576;
    float ssq = 0.f, vsp = 0.f;
    uint32_t* qb_out = qb_pack + (size_t)blk * 8192;
    for (int h = 0; h < 2; ++h){
        __syncthreads();                   // Wq ready (h=0) / prev compute done (h=1)
        // stage half: 2048 float4, 4 per thread
        #pragma unroll
        for (int m = 0; m < 4; ++m){
            int L4 = m*512 + t;
            int f4 = L4 & 1, iw = (L4 >> 1) & 7, ihl = (L4 >> 4) & 3, c = L4 >> 6;
            const float* src = qbase + c*32768 + (bh*8 + h*4 + ihl)*1024
                             + (bw*8 + iw)*32 + bd*8 + f4*4;
            float4 v = *(const float4*)src;
            *(float4*)&q_s[c*256 + ihl*64 + iw*8 + f4*4] = v;
        }
        __syncthreads();
        for (int it = 0; it < 16; ++it){
            int jl = it*16 + sub;
            float acc = bq_s[d];
            #pragma unroll
            for (int c = 0; c < 32; ++c)
                acc += q_s[c*256 + jl] * Wq_s[c*32 + d];
            ssq += acc * acc;
            vsp += acc;
            float accO = __shfl_xor(acc, 1, 64);
            if ((d & 1) == 0) qb_out[(h*256 + jl)*16 + (d >> 1)] = pack2(acc, accO);
        }
    }
    red[sub][d] = ssq;
    vsx[sub][d] = vsp;
    __syncthreads();
    if (sub == 0){
        float tot = 0.f, vtot = 0.f;
        #pragma unroll
        for (int u = 0; u < 16; ++u){ tot += red[u][d]; vtot += vsx[u][d]; }
        qn_s[d] = sqrtf(tot);
        vsum[blk*32 + d] = vtot;
    }
    __syncthreads();
    if (t == 0){
        float s = 0.f;
        for (int d2 = 0; d2 < 32; ++d2) s += knorm[b*32 + d2] * qn_s[d2];
        denomv[blk] = s + 1e-4f;
    }
}

// ---------------- K4: MFMA attention, full-i, writes finished o (c-major) ----------------
// grid 512 = (bg, j-quarter); block 256 = 4 waves; LDS 56.5 KB -> 2 blocks/CU.
__global__ __launch_bounds__(256) void k_attn_mfma(const uint32_t* __restrict__ kf_pack,
    const uint32_t* __restrict__ qb_pack, const float* __restrict__ denomv,
    const float* __restrict__ vsum, float* __restrict__ oraw)
{
    __shared__ uint32_t kfs32[4096];     // kf chunk [256 i][16 dp] swizzled
    __shared__ uint16_t qbV16[16384];    // qb^T [c 32][i 512] swizzled (A & V roles)
    __shared__ uint16_t Ps16[4096];      // per-wave P [16 j][64 i]
    __shared__ float dens[64];           // per-wave 16 j-denoms
    int t = threadIdx.x;
    int blk = blockIdx.x;
    int bg = blk >> 2, jq = blk & 2 ? (blk & 3) : (blk & 3);   // jq = blk & 3
    jq = blk & 3;
    int b = bg >> 6;
    // ---- stage qbV (full 512 i) ----
    {
        const uint32_t* src = qb_pack + (size_t)bg*8192;
        for (int m = 0; m < 32; ++m){
            int flat = m*256 + t;
            int i = flat >> 4, dp = flat & 15;
            uint32_t v = src[flat];
            int d0 = 2*dp, d1 = 2*dp + 1;
            qbV16[d0*512 + (((i>>3) ^ (d0&7)) & 63)*8 + (i&7)] = (uint16_t)(v & 0xffffu);
            qbV16[d1*512 + (((i>>3) ^ (d1&7)) & 63)*8 + (i&7)] = (uint16_t)(v >> 16);
        }
    }
    // ---- stage kf chunk 0 ----
    {
        const uint32_t* src = kf_pack + b*8192;
        for (int m = 0; m < 16; ++m){
            int flat = m*256 + t;
            uint32_t v = src[flat];
            int i = flat >> 4, dp = flat & 15;
            kfs32[i*16 + (((dp>>2) ^ (i&3)) & 3)*4 + (dp&3)] = v;
        }
    }
    __syncthreads();
    float rden = 1.0f / denomv[bg];
    int wave = t >> 6, lane = t & 63;
    int ln15 = lane & 15, quad = lane >> 4;
    uint16_t* Pw = Ps16 + wave*1024;
    // vsum for this lane's 8 output channels
    float vs0[4], vs1[4];
    #pragma unroll
    for (int r = 0; r < 4; ++r){
        vs0[r] = vsum[bg*32 + quad*4 + r];
        vs1[r] = vsum[bg*32 + 16 + quad*4 + r];
    }
    // A-fragments for this wave's two j-tiles (j global within bg)
    union { bf16x8 v; uint16_t u[8]; } afr[2];
    #pragma unroll
    for (int jt2 = 0; jt2 < 2; ++jt2){
        int j = jq*128 + (wave*2 + jt2)*16 + ln15;
        #pragma unroll
        for (int jj = 0; jj < 8; ++jj){
            int d = quad*8 + jj;
            afr[jt2].u[jj] = qbV16[d*512 + (((j>>3) ^ (d&7)) & 63)*8 + (j&7)];
        }
    }
    f32x4 pv0[2] = {{0.f,0.f,0.f,0.f},{0.f,0.f,0.f,0.f}};
    f32x4 pv1[2] = {{0.f,0.f,0.f,0.f},{0.f,0.f,0.f,0.f}};
    float pdn[2][4] = {{0.f,0.f,0.f,0.f},{0.f,0.f,0.f,0.f}};
    for (int ic = 0; ic < 2; ++ic){
        if (ic == 1){
            __syncthreads();     // all waves done with chunk 0
            const uint32_t* src = kf_pack + b*8192 + 4096;
            for (int m = 0; m < 16; ++m){
                int flat = m*256 + t;
                uint32_t v = src[flat];
                int i = flat >> 4, dp = flat & 15;
                kfs32[i*16 + (((dp>>2) ^ (i&3)) & 3)*4 + (dp&3)] = v;
            }
            __syncthreads();
        }
        #pragma unroll
        for (int jt2 = 0; jt2 < 2; ++jt2){
            for (int sb = 0; sb < 2; ++sb){
                // sim: 8 i-tiles (128 i of this chunk)
                f32x4 sacc[8];
                #pragma unroll
                for (int u = 0; u < 8; ++u){
                    int i = (sb*8 + u)*16 + ln15;
                    bf16x8 bfr = *(__shared__ bf16x8*)&kfs32[i*16 + ((quad ^ (i&3)) & 3)*4];
                    f32x4 z = {0.f,0.f,0.f,0.f};
                    sacc[u] = __builtin_amdgcn_mfma_f32_16x16x32_bf16(afr[jt2].v, bfr, z, 0, 0, 0);
                }
                #pragma unroll
                for (int h2 = 0; h2 < 2; ++h2){
                    // e = expm1(x) for 4 i-tiles -> P chunk [16 j][64 i]
                    #pragma unroll
                    for (int u4 = 0; u4 < 4; ++u4){
                        int u = h2*4 + u4;
                        int il = u4*16 + ln15;
                        #pragma unroll
                        for (int r = 0; r < 4; ++r){
                            float x = sacc[u][r] * rden;
                            float e = x + x*x*(0.5f + x*(1.0f/6.0f));
                            pdn[jt2][r] += e;
                            int jrow = quad*4 + r;
                            Pw[jrow*64 + (((il>>3) ^ (jrow&3)) & 7)*8 + (il&7)] = (uint16_t)f2bf(e);
                        }
                    }
                    __threadfence_block();
                    // PV: 2 ksteps of 32 i
                    #pragma unroll
                    for (int ks = 0; ks < 2; ++ks){
                        int i0 = ks*32 + quad*8;
                        bf16x8 bp = *(__shared__ bf16x8*)&Pw[ln15*64 + (((i0>>3) ^ (ln15&3)) & 7)*8];
                        int ig = ic*256 + sb*128 + h2*64 + i0;
                        int c0 = ln15, c1 = 16 + ln15;
                        bf16x8 av0 = *(__shared__ bf16x8*)&qbV16[c0*512 + (((ig>>3) ^ (c0&7)) & 63)*8];
                        bf16x8 av1 = *(__shared__ bf16x8*)&qbV16[c1*512 + (((ig>>3) ^ (c1&7)) & 63)*8];
                        pv0[jt2] = __builtin_amdgcn_mfma_f32_16x16x32_bf16(av0, bp, pv0[jt2], 0, 0, 0);
                        pv1[jt2] = __builtin_amdgcn_mfma_f32_16x16x32_bf16(av1, bp, pv1[jt2], 0, 0, 0);
                    }
                }
            }
        }
    }
    // ---- finish: denominators + o write (c-major) ----
    float* obase = oraw + (size_t)bg * 16384;
    #pragma unroll
    for (int jt2 = 0; jt2 < 2; ++jt2){
        #pragma unroll
        for (int r = 0; r < 4; ++r){
            float s = pdn[jt2][r];
            s += __shfl_xor(s, 1, 64);
            s += __shfl_xor(s, 2, 64);
            s += __shfl_xor(s, 4, 64);
            s += __shfl_xor(s, 8, 64);
            if (ln15 == 0) dens[wave*16 + quad*4 + r] = s;
        }
        __threadfence_block();
        float rl = 1.0f / (512.f + dens[wave*16 + ln15]);
        int jglob = jq*128 + (wave*2 + jt2)*16 + ln15;
        #pragma unroll
        for (int r = 0; r < 4; ++r){
            obase[(quad*4 + r)*512 + jglob]      = (vs0[r] + pv0[jt2][r]) * rl;
            obase[(16 + quad*4 + r)*512 + jglob] = (vs1[r] + pv1[jt2][r]) * rl;
        }
        __threadfence_block();   // dens reuse guard between jt2 iterations
    }
}

// ---------------- K5: row stats per (bg,c): mn, 1/(mx-mn+eps) ----------------
__global__ __launch_bounds__(256) void k_rstat(const float* __restrict__ oraw,
    float* __restrict__ mn_s, float* __restrict__ sc_s)
{
    int blk = blockIdx.x;                        // 512 blocks
    int bg = blk >> 2, c = (blk & 3)*8 + (threadIdx.x >> 5);
    int l = threadIdx.x & 31;
    const float* row = oraw + (size_t)bg*16384 + (size_t)c*512;
    float mn = 3e38f, mx = -3e38f;
    #pragma unroll
    for (int it = 0; it < 16; ++it){
        float v = row[l + it*32];
        mn = fminf(mn, v); mx = fmaxf(mx, v);
    }
    #pragma unroll
    for (int off = 16; off > 0; off >>= 1){
        mn = fminf(mn, __shfl_xor(mn, off, 32));
        mx = fmaxf(mx, __shfl_xor(mx, off, 32));
    }
    if (l == 0){
        mn_s[bg*32 + c] = mn;
        sc_s[bg*32 + c] = 1.0f / (mx - mn + 1e-4f);
    }
}

// ---------------- K6: scrambled gather + fused renorm + Wp projection ----------------
__global__ __launch_bounds__(256) void k_proj(const float* __restrict__ oraw,
    const float* __restrict__ mn_s, const float* __restrict__ sc_s,
    const float* __restrict__ Wp, const float* __restrict__ bp,
    float* __restrict__ out)
{
    __shared__ float Wp_s[1024], bp_s[32];
    __shared__ float sh_v[8][32], sh_o[8][32];
    int t = threadIdx.x;
    if (t < 32) bp_s[t] = bp[t];
    for (int L = t; L < 1024; L += 256) Wp_s[L] = Wp[L];
    int blk = blockIdx.x;                        // 8192 blocks
    int b = blk >> 12, p0 = (blk & 4095) * 8;
    int c = t & 31, ip = t >> 5;
    int p = p0 + ip;
    int h = p >> 10, w = (p >> 5) & 31, dsp = p & 31;
    int f = (h >> 3)*262144 + (w >> 3)*65536 + (dsp >> 3)*16384
          + (h & 7)*2048 + (w & 7)*256 + (dsp & 7)*32;
    int flat = f + c;                            // within-batch flat index
    int cidx = flat >> 9;                        // = g*32 + true-channel
    float o  = oraw[(size_t)b * 1048576 + flat];
    float vv = (o - mn_s[b*2048 + cidx]) * sc_s[b*2048 + cidx];
    __syncthreads();
    sh_v[ip][c] = vv;
    __syncthreads();
    float acc = bp_s[c];
    #pragma unroll
    for (int cc = 0; cc < 32; ++cc)
        acc += sh_v[ip][cc] * Wp_s[cc*32 + c];
    sh_o[ip][c] = acc;
    __syncthreads();
    int ee = t >> 3, pi = t & 7;
    out[((size_t)(b*32 + ee) << 15) + p0 + pi] = sh_o[pi][ee];
}

extern "C" void kernel_launch(void* const* d_in, const int* in_sizes, int n_in,
                              void* d_out, int out_size, void* d_ws, size_t ws_size,
                              hipStream_t stream)
{
    const float* q  = (const float*)d_in[0];
    const float* k  = (const float*)d_in[1];
    const float* Wq = (const float*)d_in[2];
    const float* bq = (const float*)d_in[3];
    const float* Wk = (const float*)d_in[4];
    const float* bk = (const float*)d_in[5];
    const float* Wp = (const float*)d_in[6];
    const float* bp = (const float*)d_in[7];

    float* base      = (float*)d_ws;
    float* kf_f      = base;                            // 32768 f
    float* knorm     = base + 32768;                    // 64 f
    float* denomv    = base + 32832;                    // 128 f
    float* vsum      = base + 32960;                    // 4096 f
    float* mn_s      = base + 37056;                    // 4096 f
    float* sc_s      = base + 41152;                    // 4096 f
    uint32_t* kf_pack = (uint32_t*)(base + 45248);      // 16384 u32
    uint32_t* qb_pack = (uint32_t*)(base + 61632);      // 1,048,576 u32
    float* oraw      = base + 1110208;                  // 2,097,152 f  (~12.8 MB total)
    float* outp      = (float*)d_out;

    hipLaunchKernelGGL(k_kf,        dim3(128),  dim3(256), 0, stream, k, Wk, bk, kf_f, kf_pack);
    hipLaunchKernelGGL(k_knorm,     dim3(2),    dim3(256), 0, stream, kf_f, knorm);
    hipLaunchKernelGGL(k_qb,        dim3(128),  dim3(512), 0, stream, q, Wq, bq, knorm, qb_pack, denomv, vsum);
    hipLaunchKernelGGL(k_attn_mfma, dim3(512),  dim3(256), 0, stream, kf_pack, qb_pack, denomv, vsum, oraw);
    hipLaunchKernelGGL(k_rstat,     dim3(512),  dim3(256), 0, stream, oraw, mn_s, sc_s);
    hipLaunchKernelGGL(k_proj,      dim3(8192), dim3(256), 0, stream, oraw, mn_s, sc_s, Wp, bp, outp);
}

// Round 11
// 143.324 us; speedup vs baseline: 4.2220x; 1.0008x over previous
//
#include <hip/hip_runtime.h>
#include <hip/hip_bf16.h>
#include <cstdint>

typedef __attribute__((ext_vector_type(8))) short bf16x8;
typedef __attribute__((ext_vector_type(4))) float f32x4;

static __device__ __forceinline__ uint32_t f2bf(float x){
    uint32_t u = __float_as_uint(x);
    return (u + 0x7fffu + ((u >> 16) & 1u)) >> 16;
}
static __device__ __forceinline__ uint32_t pack2(float a, float b){
    return f2bf(a) | (f2bf(b) << 16);
}
// monotone float->int key: ordering of floats == ordering of keys as signed ints
static __device__ __forceinline__ int fkey(float f){
    int i = __float_as_int(f);
    return i >= 0 ? i : (i ^ 0x7fffffff);
}
static __device__ __forceinline__ float funkey(int k){
    return __int_as_float(k >= 0 ? k : (k ^ 0x7fffffff));
}

// ---------------- K1: kf packed bf16 + knorm2 atomic partials ----------------
__global__ __launch_bounds__(256) void k_kf(const float* __restrict__ k,
    const float* __restrict__ Wk, const float* __restrict__ bk,
    uint32_t* __restrict__ kf_pack, float* __restrict__ knorm2)
{
    __shared__ float Wk_s[256*32];
    __shared__ float bk_s[32];
    __shared__ float red[8][32];
    int t = threadIdx.x;
    for (int L = t; L < 8192; L += 256) Wk_s[L] = Wk[L];
    if (t < 32) bk_s[t] = bk[t];
    __syncthreads();
    int blk = blockIdx.x;                 // 128 blocks
    int b = blk >> 6, i0 = (blk & 63) * 8;
    int d = t & 31, sub = t >> 5;
    int i = i0 + sub;
    const float* kb = k + (size_t)b * 131072;
    float acc = bk_s[d];
    #pragma unroll 8
    for (int c = 0; c < 256; ++c)
        acc += kb[c*512 + i] * Wk_s[c*32 + d];
    float accO = __shfl_xor(acc, 1, 64);       // lane parity == d parity
    if ((d & 1) == 0)
        kf_pack[(b*512 + i)*16 + (d >> 1)] = pack2(acc, accO);
    red[sub][d] = acc * acc;
    __syncthreads();
    if (sub == 0){
        float tot = 0.f;
        #pragma unroll
        for (int u = 0; u < 8; ++u) tot += red[u][d];
        atomicAdd(&knorm2[b*32 + d], tot);
    }
}

// ---------------- K2: qb packed bf16 + qn2/vsum atomic partials ----------------
// grid 256 = (bg, j-half); block 256
__global__ __launch_bounds__(256) void k_qb(const float* __restrict__ q,
    const float* __restrict__ Wq, const float* __restrict__ bq,
    uint32_t* __restrict__ qb_pack, float* __restrict__ qn2,
    float* __restrict__ vsum)
{
    __shared__ float Wq_s[1024], bq_s[32], q_s[8192];   // q_s: 32 c x 256 j
    __shared__ float red[8][32], vsx[8][32];
    int t = threadIdx.x;
    int blk = blockIdx.x;
    int bg = blk >> 1, h = blk & 1;
    int b = bg >> 6, g = bg & 63;
    int bh = g >> 4, bw = (g >> 2) & 3, bd = g & 3;
    for (int L = t; L < 1024; L += 256) Wq_s[L] = Wq[L];
    if (t < 32) bq_s[t] = bq[t];
    const float* qbase = q + (size_t)b * 1048576;
    // stage this j-half: 2048 float4
    #pragma unroll
    for (int m = 0; m < 8; ++m){
        int L4 = m*256 + t;
        int f4 = L4 & 1, iw = (L4 >> 1) & 7, ihl = (L4 >> 4) & 3, c = L4 >> 6;
        const float* src = qbase + c*32768 + (bh*8 + h*4 + ihl)*1024
                         + (bw*8 + iw)*32 + bd*8 + f4*4;
        float4 v = *(const float4*)src;
        *(float4*)&q_s[c*256 + ihl*64 + iw*8 + f4*4] = v;
    }
    __syncthreads();
    int d = t & 31, sub = t >> 5;          // sub 0..7
    float ssq = 0.f, vsp = 0.f;
    uint32_t* qb_out = qb_pack + (size_t)bg * 8192 + h*4096;
    for (int it = 0; it < 32; ++it){
        int jl = it*8 + sub;
        float acc = bq_s[d];
        #pragma unroll
        for (int c = 0; c < 32; ++c)
            acc += q_s[c*256 + jl] * Wq_s[c*32 + d];
        ssq += acc * acc;
        vsp += acc;
        float accO = __shfl_xor(acc, 1, 64);
        if ((d & 1) == 0) qb_out[jl*16 + (d >> 1)] = pack2(acc, accO);
    }
    red[sub][d] = ssq;
    vsx[sub][d] = vsp;
    __syncthreads();
    if (sub == 0){
        float tot = 0.f, vtot = 0.f;
        #pragma unroll
        for (int u = 0; u < 8; ++u){ tot += red[u][d]; vtot += vsx[u][d]; }
        atomicAdd(&qn2[bg*32 + d], tot);
        atomicAdd(&vsum[bg*32 + d], vtot);
    }
}

// ---------------- K3: MFMA attention + inline denom + fused min/max stats ----------------
// grid 512 = (bg, j-quarter); block 256 = 4 waves
__global__ __launch_bounds__(256) void k_attn_mfma(const uint32_t* __restrict__ kf_pack,
    const uint32_t* __restrict__ qb_pack, const float* __restrict__ knorm2,
    const float* __restrict__ qn2, const float* __restrict__ vsum,
    float* __restrict__ oraw, int* __restrict__ mnkey, int* __restrict__ mxkey)
{
    __shared__ uint32_t kfs32[4096];     // kf chunk [256 i][16 dp] swizzled
    __shared__ uint16_t qbV16[16384];    // qb^T [c 32][i 512] swizzled (A & V roles)
    __shared__ uint16_t Ps16[4096];      // per-wave P [16 j][64 i]
    __shared__ float dens[64];
    __shared__ float dsh[32];
    __shared__ float denom_s;
    int t = threadIdx.x;
    int blk = blockIdx.x;
    int bg = blk >> 2, jq = blk & 3;
    int b = bg >> 6;
    if (t < 32) dsh[t] = sqrtf(knorm2[b*32 + t]) * sqrtf(qn2[bg*32 + t]);
    // ---- stage qbV (full 512 i) ----
    {
        const uint32_t* src = qb_pack + (size_t)bg*8192;
        for (int m = 0; m < 32; ++m){
            int flat = m*256 + t;
            int i = flat >> 4, dp = flat & 15;
            uint32_t v = src[flat];
            int d0 = 2*dp, d1 = 2*dp + 1;
            qbV16[d0*512 + (((i>>3) ^ (d0&7)) & 63)*8 + (i&7)] = (uint16_t)(v & 0xffffu);
            qbV16[d1*512 + (((i>>3) ^ (d1&7)) & 63)*8 + (i&7)] = (uint16_t)(v >> 16);
        }
    }
    // ---- stage kf chunk 0 ----
    {
        const uint32_t* src = kf_pack + b*8192;
        for (int m = 0; m < 16; ++m){
            int flat = m*256 + t;
            uint32_t v = src[flat];
            int i = flat >> 4, dp = flat & 15;
            kfs32[i*16 + (((dp>>2) ^ (i&3)) & 3)*4 + (dp&3)] = v;
        }
    }
    __syncthreads();
    if (t == 0){
        float s = 0.f;
        #pragma unroll
        for (int d2 = 0; d2 < 32; ++d2) s += dsh[d2];
        denom_s = s + 1e-4f;
    }
    __syncthreads();
    float rden = 1.0f / denom_s;
    int wave = t >> 6, lane = t & 63;
    int ln15 = lane & 15, quad = lane >> 4;
    uint16_t* Pw = Ps16 + wave*1024;
    float vs0[4], vs1[4];
    #pragma unroll
    for (int r = 0; r < 4; ++r){
        vs0[r] = vsum[bg*32 + quad*4 + r];
        vs1[r] = vsum[bg*32 + 16 + quad*4 + r];
    }
    union { bf16x8 v; uint16_t u[8]; } afr[2];
    #pragma unroll
    for (int jt2 = 0; jt2 < 2; ++jt2){
        int j = jq*128 + (wave*2 + jt2)*16 + ln15;
        #pragma unroll
        for (int jj = 0; jj < 8; ++jj){
            int d = quad*8 + jj;
            afr[jt2].u[jj] = qbV16[d*512 + (((j>>3) ^ (d&7)) & 63)*8 + (j&7)];
        }
    }
    f32x4 pv0[2] = {{0.f,0.f,0.f,0.f},{0.f,0.f,0.f,0.f}};
    f32x4 pv1[2] = {{0.f,0.f,0.f,0.f},{0.f,0.f,0.f,0.f}};
    float pdn[2][4] = {{0.f,0.f,0.f,0.f},{0.f,0.f,0.f,0.f}};
    for (int ic = 0; ic < 2; ++ic){
        if (ic == 1){
            __syncthreads();
            const uint32_t* src = kf_pack + b*8192 + 4096;
            for (int m = 0; m < 16; ++m){
                int flat = m*256 + t;
                uint32_t v = src[flat];
                int i = flat >> 4, dp = flat & 15;
                kfs32[i*16 + (((dp>>2) ^ (i&3)) & 3)*4 + (dp&3)] = v;
            }
            __syncthreads();
        }
        #pragma unroll
        for (int jt2 = 0; jt2 < 2; ++jt2){
            for (int sb = 0; sb < 2; ++sb){
                f32x4 sacc[8];
                #pragma unroll
                for (int u = 0; u < 8; ++u){
                    int i = (sb*8 + u)*16 + ln15;
                    bf16x8 bfr = *(__shared__ bf16x8*)&kfs32[i*16 + ((quad ^ (i&3)) & 3)*4];
                    f32x4 z = {0.f,0.f,0.f,0.f};
                    sacc[u] = __builtin_amdgcn_mfma_f32_16x16x32_bf16(afr[jt2].v, bfr, z, 0, 0, 0);
                }
                #pragma unroll
                for (int h2 = 0; h2 < 2; ++h2){
                    #pragma unroll
                    for (int u4 = 0; u4 < 4; ++u4){
                        int u = h2*4 + u4;
                        int il = u4*16 + ln15;
                        #pragma unroll
                        for (int r = 0; r < 4; ++r){
                            float x = sacc[u][r] * rden;
                            float e = x + x*x*(0.5f + x*(1.0f/6.0f));
                            pdn[jt2][r] += e;
                            int jrow = quad*4 + r;
                            Pw[jrow*64 + (((il>>3) ^ (jrow&3)) & 7)*8 + (il&7)] = (uint16_t)f2bf(e);
                        }
                    }
                    __threadfence_block();
                    #pragma unroll
                    for (int ks = 0; ks < 2; ++ks){
                        int i0 = ks*32 + quad*8;
                        bf16x8 bp = *(__shared__ bf16x8*)&Pw[ln15*64 + (((i0>>3) ^ (ln15&3)) & 7)*8];
                        int ig = ic*256 + sb*128 + h2*64 + i0;
                        int c0 = ln15, c1 = 16 + ln15;
                        bf16x8 av0 = *(__shared__ bf16x8*)&qbV16[c0*512 + (((ig>>3) ^ (c0&7)) & 63)*8];
                        bf16x8 av1 = *(__shared__ bf16x8*)&qbV16[c1*512 + (((ig>>3) ^ (c1&7)) & 63)*8];
                        pv0[jt2] = __builtin_amdgcn_mfma_f32_16x16x32_bf16(av0, bp, pv0[jt2], 0, 0, 0);
                        pv1[jt2] = __builtin_amdgcn_mfma_f32_16x16x32_bf16(av1, bp, pv1[jt2], 0, 0, 0);
                    }
                }
            }
        }
    }
    // ---- finish: denominators + o write (c-major) + fused min/max stats ----
    float* obase = oraw + (size_t)bg * 16384;
    #pragma unroll
    for (int jt2 = 0; jt2 < 2; ++jt2){
        #pragma unroll
        for (int r = 0; r < 4; ++r){
            float s = pdn[jt2][r];
            s += __shfl_xor(s, 1, 64);
            s += __shfl_xor(s, 2, 64);
            s += __shfl_xor(s, 4, 64);
            s += __shfl_xor(s, 8, 64);
            if (ln15 == 0) dens[wave*16 + quad*4 + r] = s;
        }
        __threadfence_block();
        float rl = 1.0f / (512.f + dens[wave*16 + ln15]);
        int jglob = jq*128 + (wave*2 + jt2)*16 + ln15;
        float o0[4], o1[4];
        #pragma unroll
        for (int r = 0; r < 4; ++r){
            o0[r] = (vs0[r] + pv0[jt2][r]) * rl;
            o1[r] = (vs1[r] + pv1[jt2][r]) * rl;
            obase[(quad*4 + r)*512 + jglob]      = o0[r];
            obase[(16 + quad*4 + r)*512 + jglob] = o1[r];
        }
        // min/max over the 16 j's of this tile per c-row, then atomic merge
        #pragma unroll
        for (int r = 0; r < 4; ++r){
            float mnA = o0[r], mxA = o0[r], mnB = o1[r], mxB = o1[r];
            #pragma unroll
            for (int off = 1; off < 16; off <<= 1){
                mnA = fminf(mnA, __shfl_xor(mnA, off, 64));
                mxA = fmaxf(mxA, __shfl_xor(mxA, off, 64));
                mnB = fminf(mnB, __shfl_xor(mnB, off, 64));
                mxB = fmaxf(mxB, __shfl_xor(mxB, off, 64));
            }
            if (ln15 == 0){
                atomicMin(&mnkey[bg*32 + quad*4 + r],      fkey(mnA));
                atomicMax(&mxkey[bg*32 + quad*4 + r],      fkey(mxA));
                atomicMin(&mnkey[bg*32 + 16 + quad*4 + r], fkey(mnB));
                atomicMax(&mxkey[bg*32 + 16 + quad*4 + r], fkey(mxB));
            }
        }
        __threadfence_block();   // dens reuse guard between jt2 iterations
    }
}

// ---------------- K4: scrambled gather + fused renorm + Wp projection ----------------
// grid 2048; block 256; 32 positions/block, 4 gathers+outputs per thread
__global__ __launch_bounds__(256) void k_proj(const float* __restrict__ oraw,
    const int* __restrict__ mnkey, const int* __restrict__ mxkey,
    const float* __restrict__ Wp, const float* __restrict__ bp,
    float* __restrict__ out)
{
    __shared__ float Wp_s[1024], bp_s[32];
    __shared__ float sh_v[32][32];
    __shared__ float sh_o[32][33];
    int t = threadIdx.x;
    if (t < 32) bp_s[t] = bp[t];
    for (int L = t; L < 1024; L += 256) Wp_s[L] = Wp[L];
    int blk = blockIdx.x;
    int b = blk >> 10, p0 = (blk & 1023) * 32;
    int c = t & 31, ip0 = t >> 5;
    float vv[4];
    #pragma unroll
    for (int m = 0; m < 4; ++m){
        int p = p0 + m*8 + ip0;
        int h = p >> 10, w = (p >> 5) & 31, dsp = p & 31;
        int f = (h >> 3)*262144 + (w >> 3)*65536 + (dsp >> 3)*16384
              + (h & 7)*2048 + (w & 7)*256 + (dsp & 7)*32;
        int flat = f + c;
        int cidx = b*2048 + (flat >> 9);
        float o = oraw[(size_t)b*1048576 + flat];
        float mn = funkey(mnkey[cidx]);
        float mx = funkey(mxkey[cidx]);
        vv[m] = (o - mn) / (mx - mn + 1e-4f);
    }
    __syncthreads();
    #pragma unroll
    for (int m = 0; m < 4; ++m) sh_v[m*8 + ip0][c] = vv[m];
    __syncthreads();
    #pragma unroll
    for (int m = 0; m < 4; ++m){
        int pos = m*8 + ip0;
        float acc = bp_s[c];
        #pragma unroll
        for (int cc = 0; cc < 32; ++cc)
            acc += sh_v[pos][cc] * Wp_s[cc*32 + c];
        sh_o[pos][c] = acc;
    }
    __syncthreads();
    #pragma unroll
    for (int m = 0; m < 4; ++m){
        int e = m*8 + (t >> 5), pi = t & 31;
        out[((size_t)(b*32 + e) << 15) + p0 + pi] = sh_o[pi][e];
    }
}

extern "C" void kernel_launch(void* const* d_in, const int* in_sizes, int n_in,
                              void* d_out, int out_size, void* d_ws, size_t ws_size,
                              hipStream_t stream)
{
    const float* q  = (const float*)d_in[0];
    const float* k  = (const float*)d_in[1];
    const float* Wq = (const float*)d_in[2];
    const float* bq = (const float*)d_in[3];
    const float* Wk = (const float*)d_in[4];
    const float* bk = (const float*)d_in[5];
    const float* Wp = (const float*)d_in[6];
    const float* bp = (const float*)d_in[7];

    float* base      = (float*)d_ws;
    float* knorm2    = base;                            // 64 f      (zero-init)
    float* qn2       = base + 64;                       // 4096 f    (zero-init)
    float* vsum      = base + 4160;                     // 4096 f    (zero-init)
    int*   mnkey     = (int*)(base + 8256);             // 4096 i    (0x7f fill)
    int*   mxkey     = (int*)(base + 12352);            // 4096 i    (0x80 fill)
    uint32_t* kf_pack = (uint32_t*)(base + 16448);      // 16384 u32
    uint32_t* qb_pack = (uint32_t*)(base + 32832);      // 1,048,576 u32
    float* oraw      = base + 1081408;                  // 2,097,152 f (~12.7 MB total)
    float* outp      = (float*)d_out;

    hipMemsetAsync(base, 0, 8256*4, stream);            // knorm2+qn2+vsum
    hipMemsetAsync(mnkey, 0x7f, 4096*4, stream);        // +large int keys
    hipMemsetAsync(mxkey, 0x80, 4096*4, stream);        // -large int keys

    hipLaunchKernelGGL(k_kf,        dim3(128),  dim3(256), 0, stream, k, Wk, bk, kf_pack, knorm2);
    hipLaunchKernelGGL(k_qb,        dim3(256),  dim3(256), 0, stream, q, Wq, bq, qb_pack, qn2, vsum);
    hipLaunchKernelGGL(k_attn_mfma, dim3(512),  dim3(256), 0, stream, kf_pack, qb_pack, knorm2, qn2, vsum, oraw, mnkey, mxkey);
    hipLaunchKernelGGL(k_proj,      dim3(2048), dim3(256), 0, stream, oraw, mnkey, mxkey, Wp, bp, outp);
}

// Round 12
// 135.645 us; speedup vs baseline: 4.4610x; 1.0566x over previous
//
#include <hip/hip_runtime.h>
#include <hip/hip_bf16.h>
#include <cstdint>

typedef __attribute__((ext_vector_type(8))) short bf16x8;
typedef __attribute__((ext_vector_type(4))) float f32x4;

static __device__ __forceinline__ float lo16(uint32_t u){ return __uint_as_float(u << 16); }
static __device__ __forceinline__ float hi16(uint32_t u){ return __uint_as_float(u & 0xffff0000u); }
static __device__ __forceinline__ uint32_t f2bf(float x){
    uint32_t u = __float_as_uint(x);
    return (u + 0x7fffu + ((u >> 16) & 1u)) >> 16;
}
static __device__ __forceinline__ uint32_t pack2(float a, float b){
    return f2bf(a) | (f2bf(b) << 16);
}

// ---------------- K1: kf packed bf16 (pure projection) ----------------
// grid 256 = (b, 128 i-groups of 4); block 256
__global__ __launch_bounds__(256) void k_kf(const float* __restrict__ k,
    const float* __restrict__ Wk, const float* __restrict__ bk,
    uint32_t* __restrict__ kf_pack)
{
    __shared__ float Wk_s[256*32];
    __shared__ float bk_s[32];
    int t = threadIdx.x;
    for (int L = t; L < 8192; L += 256) Wk_s[L] = Wk[L];
    if (t < 32) bk_s[t] = bk[t];
    __syncthreads();
    int blk = blockIdx.x;
    int b = blk >> 7, i0 = (blk & 127) * 4;
    int d = t & 31, sub = t >> 5;
    int i = i0 + (sub >> 1);          // sub pairs (2s,2s+1) share i, split c-range
    int chalf = sub & 1;              // partner lanes differ by bit5 of t -> shfl 32
    const float* kb = k + (size_t)b * 131072;
    float acc = chalf ? 0.f : bk_s[d];
    #pragma unroll 8
    for (int cc = 0; cc < 128; ++cc){
        int c = chalf*128 + cc;
        acc += kb[c*512 + i] * Wk_s[c*32 + d];
    }
    acc += __shfl_xor(acc, 32, 64);   // combine c-halves (both lanes hold total)
    float accO = __shfl_xor(acc, 1, 64);
    if (chalf == 0 && (d & 1) == 0)
        kf_pack[(b*512 + i)*16 + (d >> 1)] = pack2(acc, accO);
}

// ---------------- K2: qb packed bf16 (pure projection) ----------------
// grid 256 = (bg, j-half); block 256
__global__ __launch_bounds__(256) void k_qb(const float* __restrict__ q,
    const float* __restrict__ Wq, const float* __restrict__ bq,
    uint32_t* __restrict__ qb_pack)
{
    __shared__ float Wq_s[1024], bq_s[32], q_s[8192];   // q_s: 32 c x 256 j
    int t = threadIdx.x;
    int blk = blockIdx.x;
    int bg = blk >> 1, h = blk & 1;
    int b = bg >> 6, g = bg & 63;
    int bh = g >> 4, bw = (g >> 2) & 3, bd = g & 3;
    for (int L = t; L < 1024; L += 256) Wq_s[L] = Wq[L];
    if (t < 32) bq_s[t] = bq[t];
    const float* qbase = q + (size_t)b * 1048576;
    #pragma unroll
    for (int m = 0; m < 8; ++m){
        int L4 = m*256 + t;
        int f4 = L4 & 1, iw = (L4 >> 1) & 7, ihl = (L4 >> 4) & 3, c = L4 >> 6;
        const float* src = qbase + c*32768 + (bh*8 + h*4 + ihl)*1024
                         + (bw*8 + iw)*32 + bd*8 + f4*4;
        float4 v = *(const float4*)src;
        *(float4*)&q_s[c*256 + ihl*64 + iw*8 + f4*4] = v;
    }
    __syncthreads();
    int d = t & 31, sub = t >> 5;          // sub 0..7
    uint32_t* qb_out = qb_pack + (size_t)bg * 8192 + h*4096;
    for (int it = 0; it < 32; ++it){
        int jl = it*8 + sub;
        float acc = bq_s[d];
        #pragma unroll
        for (int c = 0; c < 32; ++c)
            acc += q_s[c*256 + jl] * Wq_s[c*32 + d];
        float accO = __shfl_xor(acc, 1, 64);
        if ((d & 1) == 0) qb_out[jl*16 + (d >> 1)] = pack2(acc, accO);
    }
}

// ---------------- K3: self-contained MFMA attention ----------------
// grid 256 = (bg, j-half); block 256 = 4 waves; ~78 KB LDS -> 2 blocks/CU.
// Computes denom/vsum from staged bf16 data; writes o (c-major) + min/max slots.
__global__ __launch_bounds__(256) void k_attn_mfma(const uint32_t* __restrict__ kf_pack,
    const uint32_t* __restrict__ qb_pack,
    float* __restrict__ oraw, float* __restrict__ mnp, float* __restrict__ mxp)
{
    __shared__ uint32_t kfs32[8192];     // 32 KB: full kf [512 i][16 dp] swizzled
    __shared__ uint16_t qbV16[16384];    // 32 KB: qb^T [32 d][512 i] swizzled
    __shared__ uint16_t Ps16[4096];      // 8 KB: per-wave P [16 j][64 i]
    __shared__ float mred[4][4][64];     // 4 KB: per (wave,jt) {mn[32],mx[32]}
    __shared__ float stat[16][32];       // 2 KB: prologue reduce scratch
    __shared__ float dens[4][16];
    __shared__ float knsh[32], vssh[32], dsh[32];
    __shared__ float denom_s;
    int t = threadIdx.x;
    int blk = blockIdx.x;
    int bg = blk >> 1, jhalf = blk & 1;
    int b = bg >> 6;
    // ---- stage kf (full 512 i) ----
    {
        const uint32_t* src = kf_pack + b*8192;
        for (int m = 0; m < 32; ++m){
            int flat = m*256 + t;
            uint32_t v = src[flat];
            int i = flat >> 4, dp = flat & 15;
            kfs32[i*16 + (((dp>>2) ^ (i&3)) & 3)*4 + (dp&3)] = v;
        }
    }
    // ---- stage qbV (full 512 i) ----
    {
        const uint32_t* src = qb_pack + (size_t)bg*8192;
        for (int m = 0; m < 32; ++m){
            int flat = m*256 + t;
            int i = flat >> 4, dp = flat & 15;
            uint32_t v = src[flat];
            int d0 = 2*dp, d1 = 2*dp + 1;
            qbV16[d0*512 + (((i>>3) ^ (d0&7)) & 63)*8 + (i&7)] = (uint16_t)(v & 0xffffu);
            qbV16[d1*512 + (((i>>3) ^ (d1&7)) & 63)*8 + (i&7)] = (uint16_t)(v >> 16);
        }
    }
    __syncthreads();
    // ---- prologue 1: knorm2 from staged kf ----
    {
        int dp = t & 15, ig = t >> 4;            // 16 groups of 32 i
        float lo2 = 0.f, hi2 = 0.f;
        #pragma unroll 8
        for (int ii = 0; ii < 32; ++ii){
            int i = ig*32 + ii;
            uint32_t u = kfs32[i*16 + (((dp>>2) ^ (i&3)) & 3)*4 + (dp&3)];
            float a = lo16(u), c = hi16(u);
            lo2 += a*a; hi2 += c*c;
        }
        stat[ig][dp*2] = lo2; stat[ig][dp*2+1] = hi2;
    }
    __syncthreads();
    if (t < 32){
        float s = 0.f;
        #pragma unroll
        for (int u = 0; u < 16; ++u) s += stat[u][t];
        knsh[t] = s;
    }
    __syncthreads();
    // ---- prologue 2: qn2 + vsum from staged qb ----
    {
        int d = t & 31, ig = t >> 5;             // 8 groups of 64 i
        float q2 = 0.f, vs = 0.f;
        #pragma unroll 8
        for (int ii = 0; ii < 64; ii += 2){
            int i = ig*64 + ii;
            uint32_t u = *(__shared__ uint32_t*)&qbV16[d*512 + (((i>>3) ^ (d&7)) & 63)*8 + (i&7)];
            float a = lo16(u), c = hi16(u);
            q2 += a*a + c*c; vs += a + c;
        }
        stat[ig][d] = q2; stat[8 + ig][d] = vs;
    }
    __syncthreads();
    if (t < 32){
        float q2 = 0.f, vs = 0.f;
        #pragma unroll
        for (int u = 0; u < 8; ++u){ q2 += stat[u][t]; vs += stat[8+u][t]; }
        vssh[t] = vs;
        dsh[t] = sqrtf(knsh[t]) * sqrtf(q2);
    }
    __syncthreads();
    if (t == 0){
        float s = 0.f;
        #pragma unroll
        for (int d2 = 0; d2 < 32; ++d2) s += dsh[d2];
        denom_s = s + 1e-4f;
    }
    __syncthreads();
    float rden = 1.0f / denom_s;
    int wave = t >> 6, lane = t & 63;
    int ln15 = lane & 15, quad = lane >> 4;
    uint16_t* Pw = Ps16 + wave*1024;
    float vs0[4], vs1[4];
    #pragma unroll
    for (int r = 0; r < 4; ++r){
        vs0[r] = vssh[quad*4 + r];
        vs1[r] = vssh[16 + quad*4 + r];
    }
    float* obase = oraw + (size_t)bg * 16384;
    // ---- main: 4 j-tiles per wave ----
    for (int jt = 0; jt < 4; ++jt){
        int jloc = (wave*4 + jt)*16 + ln15;          // within half
        int jglob = jhalf*256 + jloc;
        union { bf16x8 v; uint16_t u[8]; } afr;
        #pragma unroll
        for (int jj = 0; jj < 8; ++jj){
            int d = quad*8 + jj;
            afr.u[jj] = qbV16[d*512 + (((jglob>>3) ^ (d&7)) & 63)*8 + (jglob&7)];
        }
        f32x4 pv0 = {0.f,0.f,0.f,0.f}, pv1 = {0.f,0.f,0.f,0.f};
        float pdn[4] = {0.f,0.f,0.f,0.f};
        for (int sb = 0; sb < 4; ++sb){              // 128 i each
            f32x4 sacc[8];
            #pragma unroll
            for (int u = 0; u < 8; ++u){
                int i = sb*128 + u*16 + ln15;
                bf16x8 bfr = *(__shared__ bf16x8*)&kfs32[i*16 + ((quad ^ (i&3)) & 3)*4];
                f32x4 z = {0.f,0.f,0.f,0.f};
                sacc[u] = __builtin_amdgcn_mfma_f32_16x16x32_bf16(afr.v, bfr, z, 0, 0, 0);
            }
            #pragma unroll
            for (int h2 = 0; h2 < 2; ++h2){
                #pragma unroll
                for (int u4 = 0; u4 < 4; ++u4){
                    int u = h2*4 + u4;
                    int il = u4*16 + ln15;
                    #pragma unroll
                    for (int r = 0; r < 4; ++r){
                        float x = sacc[u][r] * rden;
                        float e = x + x*x*(0.5f + x*(1.0f/6.0f));
                        pdn[r] += e;
                        int jrow = quad*4 + r;
                        Pw[jrow*64 + (((il>>3) ^ (jrow&3)) & 7)*8 + (il&7)] = (uint16_t)f2bf(e);
                    }
                }
                __threadfence_block();
                #pragma unroll
                for (int ks = 0; ks < 2; ++ks){
                    int i0 = ks*32 + quad*8;
                    bf16x8 bp = *(__shared__ bf16x8*)&Pw[ln15*64 + (((i0>>3) ^ (ln15&3)) & 7)*8];
                    int ig = sb*128 + h2*64 + i0;
                    int c0 = ln15, c1 = 16 + ln15;
                    bf16x8 av0 = *(__shared__ bf16x8*)&qbV16[c0*512 + (((ig>>3) ^ (c0&7)) & 63)*8];
                    bf16x8 av1 = *(__shared__ bf16x8*)&qbV16[c1*512 + (((ig>>3) ^ (c1&7)) & 63)*8];
                    pv0 = __builtin_amdgcn_mfma_f32_16x16x32_bf16(av0, bp, pv0, 0, 0, 0);
                    pv1 = __builtin_amdgcn_mfma_f32_16x16x32_bf16(av1, bp, pv1, 0, 0, 0);
                }
            }
        }
        // ---- epilogue: denom, o write, per-tile min/max ----
        #pragma unroll
        for (int r = 0; r < 4; ++r){
            float s = pdn[r];
            s += __shfl_xor(s, 1, 64);
            s += __shfl_xor(s, 2, 64);
            s += __shfl_xor(s, 4, 64);
            s += __shfl_xor(s, 8, 64);
            if (ln15 == 0) dens[wave][quad*4 + r] = s;
        }
        __threadfence_block();
        float rl = 1.0f / (512.f + dens[wave][ln15]);
        float o0[4], o1[4];
        #pragma unroll
        for (int r = 0; r < 4; ++r){
            o0[r] = (vs0[r] + pv0[r]) * rl;
            o1[r] = (vs1[r] + pv1[r]) * rl;
            obase[(quad*4 + r)*512 + jglob]      = o0[r];
            obase[(16 + quad*4 + r)*512 + jglob] = o1[r];
        }
        #pragma unroll
        for (int r = 0; r < 4; ++r){
            float mnA = o0[r], mxA = o0[r], mnB = o1[r], mxB = o1[r];
            #pragma unroll
            for (int off = 1; off < 16; off <<= 1){
                mnA = fminf(mnA, __shfl_xor(mnA, off, 64));
                mxA = fmaxf(mxA, __shfl_xor(mxA, off, 64));
                mnB = fminf(mnB, __shfl_xor(mnB, off, 64));
                mxB = fmaxf(mxB, __shfl_xor(mxB, off, 64));
            }
            if (ln15 == 0){
                mred[wave][jt][quad*4 + r]      = mnA;
                mred[wave][jt][32 + quad*4 + r] = mxA;
                mred[wave][jt][16 + quad*4 + r]      = mnB;
                mred[wave][jt][48 + quad*4 + r] = mxB;
            }
        }
        __threadfence_block();   // dens reuse guard between jt iterations
    }
    __syncthreads();
    if (t < 32){
        float mn = 3e38f, mx = -3e38f;
        #pragma unroll
        for (int w = 0; w < 4; ++w)
            #pragma unroll
            for (int j2 = 0; j2 < 4; ++j2){
                mn = fminf(mn, mred[w][j2][t]);
                mx = fmaxf(mx, mred[w][j2][32 + t]);
            }
        int slot = (bg*2 + jhalf)*32 + t;
        mnp[slot] = mn;
        mxp[slot] = mx;
    }
}

// ---------------- K4: scrambled gather + fused renorm + Wp projection ----------------
// grid 2048; block 256; 32 positions/block, 4 gathers+outputs per thread
__global__ __launch_bounds__(256) void k_proj(const float* __restrict__ oraw,
    const float* __restrict__ mnp, const float* __restrict__ mxp,
    const float* __restrict__ Wp, const float* __restrict__ bp,
    float* __restrict__ out)
{
    __shared__ float Wp_s[1024], bp_s[32];
    __shared__ float sh_v[32][32];
    __shared__ float sh_o[32][33];
    int t = threadIdx.x;
    if (t < 32) bp_s[t] = bp[t];
    for (int L = t; L < 1024; L += 256) Wp_s[L] = Wp[L];
    int blk = blockIdx.x;
    int b = blk >> 10, p0 = (blk & 1023) * 32;
    int c = t & 31, ip0 = t >> 5;
    float vv[4];
    #pragma unroll
    for (int m = 0; m < 4; ++m){
        int p = p0 + m*8 + ip0;
        int h = p >> 10, w = (p >> 5) & 31, dsp = p & 31;
        int f = (h >> 3)*262144 + (w >> 3)*65536 + (dsp >> 3)*16384
              + (h & 7)*2048 + (w & 7)*256 + (dsp & 7)*32;
        int flat = f + c;
        int cidx = b*2048 + (flat >> 9);         // bg*32 + channel
        int s0 = ((cidx >> 5) << 6) + (cidx & 31);
        float o  = oraw[(size_t)b*1048576 + flat];
        float mn = fminf(mnp[s0], mnp[s0 + 32]);
        float mx = fmaxf(mxp[s0], mxp[s0 + 32]);
        vv[m] = (o - mn) / (mx - mn + 1e-4f);
    }
    __syncthreads();
    #pragma unroll
    for (int m = 0; m < 4; ++m) sh_v[m*8 + ip0][c] = vv[m];
    __syncthreads();
    #pragma unroll
    for (int m = 0; m < 4; ++m){
        int pos = m*8 + ip0;
        float acc = bp_s[c];
        #pragma unroll
        for (int cc = 0; cc < 32; ++cc)
            acc += sh_v[pos][cc] * Wp_s[cc*32 + c];
        sh_o[pos][c] = acc;
    }
    __syncthreads();
    #pragma unroll
    for (int m = 0; m < 4; ++m){
        int e = m*8 + (t >> 5), pi = t & 31;
        out[((size_t)(b*32 + e) << 15) + p0 + pi] = sh_o[pi][e];
    }
}

extern "C" void kernel_launch(void* const* d_in, const int* in_sizes, int n_in,
                              void* d_out, int out_size, void* d_ws, size_t ws_size,
                              hipStream_t stream)
{
    const float* q  = (const float*)d_in[0];
    const float* k  = (const float*)d_in[1];
    const float* Wq = (const float*)d_in[2];
    const float* bq = (const float*)d_in[3];
    const float* Wk = (const float*)d_in[4];
    const float* bk = (const float*)d_in[5];
    const float* Wp = (const float*)d_in[6];
    const float* bp = (const float*)d_in[7];

    float* base      = (float*)d_ws;
    uint32_t* kf_pack = (uint32_t*)base;                // 16384 u32
    uint32_t* qb_pack = (uint32_t*)(base + 16384);      // 1,048,576 u32
    float* oraw      = base + 1064960;                  // 2,097,152 f
    float* mnp       = base + 3162112;                  // 8192 f
    float* mxp       = base + 3170304;                  // 8192 f (~12.7 MB total)
    float* outp      = (float*)d_out;

    hipLaunchKernelGGL(k_kf,        dim3(256),  dim3(256), 0, stream, k, Wk, bk, kf_pack);
    hipLaunchKernelGGL(k_qb,        dim3(256),  dim3(256), 0, stream, q, Wq, bq, qb_pack);
    hipLaunchKernelGGL(k_attn_mfma, dim3(256),  dim3(256), 0, stream, kf_pack, qb_pack, oraw, mnp, mxp);
    hipLaunchKernelGGL(k_proj,      dim3(2048), dim3(256), 0, stream, oraw, mnp, mxp, Wp, bp, outp);
}